// Round 1
// baseline (72.413 us; speedup 1.0000x reference)
//
#include <hip/hip_runtime.h>

// SparseLookupTable: out[b,o] = sum_k lut[inp[b,k], wgt[o,k]]
// B=512, O=1024, K=128, LUT 256x256 fp32.
// Strategy: fp16 LUT resident in LDS (128 KB), u8-packed transposed index
// tiles in LDS, 32x64 output tile per 1024-thread block, 2 outputs/thread.

#define BATCH 512
#define OUTF  1024
#define KDIM  128
#define MIDX  256

typedef _Float16 half4v __attribute__((ext_vector_type(4)));

__global__ __launch_bounds__(1024, 1)
void slt_kernel(const int* __restrict__ inp, const int* __restrict__ wgt,
                const float* __restrict__ lut, float* __restrict__ out) {
    // 128 KB fp16 LUT + 4 KB + 8 KB packed indices = 140 KB LDS (<=160 KB/CU)
    __shared__ __attribute__((aligned(16))) _Float16 lut16[MIDX * MIDX];
    __shared__ __attribute__((aligned(16))) unsigned int i_pack[32 * KDIM / 4]; // [k16][b][j] : 1024 words
    __shared__ __attribute__((aligned(16))) unsigned int w_pack[64 * KDIM / 4]; // [k16][o][j] : 2048 words

    const int tid   = threadIdx.x;
    const int otile = blockIdx.x;   // 16 tiles of 64 outputs
    const int btile = blockIdx.y;   // 16 tiles of 32 batch rows

    // ---- stage LUT fp32 -> fp16 into LDS (each thread: 16 x float4) ----
    const float4* lut4 = (const float4*)lut;
    half4v* l16v = (half4v*)lut16;
    #pragma unroll
    for (int it = 0; it < 16; ++it) {
        int idx = it * 1024 + tid;
        float4 v = lut4[idx];
        half4v h = { (_Float16)v.x, (_Float16)v.y, (_Float16)v.z, (_Float16)v.w };
        l16v[idx] = h;
    }

    // ---- stage input indices, u8-packed, transposed [k16][b][j] ----
    {
        int b  = tid >> 5;
        int k4 = tid & 31;
        const int4 iv = *(const int4*)(inp + ((size_t)(btile * 32 + b)) * KDIM + k4 * 4);
        unsigned int w = (unsigned int)(iv.x & 255)
                       | ((unsigned int)(iv.y & 255) << 8)
                       | ((unsigned int)(iv.z & 255) << 16)
                       | ((unsigned int)(iv.w & 255) << 24);
        i_pack[(k4 >> 2) * 128 + b * 4 + (k4 & 3)] = w;
    }
    // ---- stage weight indices, u8-packed, transposed [k16][o][j] ----
    #pragma unroll
    for (int s = 0; s < 2; ++s) {
        int t2 = tid + s * 1024;
        int o  = t2 >> 5;
        int k4 = t2 & 31;
        const int4 wv = *(const int4*)(wgt + ((size_t)(otile * 64 + o)) * KDIM + k4 * 4);
        unsigned int w = (unsigned int)(wv.x & 255)
                       | ((unsigned int)(wv.y & 255) << 8)
                       | ((unsigned int)(wv.z & 255) << 16)
                       | ((unsigned int)(wv.w & 255) << 24);
        w_pack[(k4 >> 2) * 256 + o * 4 + (k4 & 3)] = w;
    }

    __syncthreads();

    const int bl = tid >> 5;   // 0..31 batch row within tile
    const int ol = tid & 31;   // output col; handles ol and ol+32

    float acc0 = 0.f, acc1 = 0.f;

    for (int k16 = 0; k16 < 8; ++k16) {
        // broadcast read (2 distinct addrs per wave) + conflict-free strided reads
        uint4 iw = ((const uint4*)i_pack)[k16 * 32 + bl];
        uint4 wa = ((const uint4*)w_pack)[k16 * 64 + ol];
        uint4 wb = ((const uint4*)w_pack)[k16 * 64 + ol + 32];
        unsigned int ia[4] = { iw.x, iw.y, iw.z, iw.w };
        unsigned int a0[4] = { wa.x, wa.y, wa.z, wa.w };
        unsigned int a1[4] = { wb.x, wb.y, wb.z, wb.w };
        #pragma unroll
        for (int j = 0; j < 4; ++j) {
            #pragma unroll
            for (int jj = 0; jj < 4; ++jj) {
                unsigned int sh  = 8u * jj;
                unsigned int row = ((ia[j] >> sh) & 255u) << 8;
                unsigned int c0  = (a0[j] >> sh) & 255u;
                unsigned int c1  = (a1[j] >> sh) & 255u;
                acc0 += (float)lut16[row + c0];
                acc1 += (float)lut16[row + c1];
            }
        }
    }

    size_t ob = ((size_t)(btile * 32 + bl)) * OUTF + (size_t)(otile * 64) + ol;
    out[ob]      = acc0;
    out[ob + 32] = acc1;
}

extern "C" void kernel_launch(void* const* d_in, const int* in_sizes, int n_in,
                              void* d_out, int out_size, void* d_ws, size_t ws_size,
                              hipStream_t stream) {
    const int*   inp = (const int*)d_in[0];    // (512, 32, 4) int32
    const int*   wgt = (const int*)d_in[1];    // (1024, 32, 4) int32
    const float* lut = (const float*)d_in[2];  // (256, 256) fp32
    float*       out = (float*)d_out;          // (512, 1024) fp32

    dim3 grid(16, 16);
    dim3 block(1024);
    slt_kernel<<<grid, block, 0, stream>>>(inp, wgt, lut, out);
}